// Round 10
// baseline (140.495 us; speedup 1.0000x reference)
//
#include <hip/hip_runtime.h>
#include <hip/hip_bf16.h>
#include <math.h>

#define NBATCH 32
#define IMGSZ  224
#define NR     400
#define NA     1024
#define ED     96
#define SROW   256   // s_samp row stride: 4 wave-private slabs of 64 cols

typedef __attribute__((ext_vector_type(8))) __bf16 bf16x8;
typedef __attribute__((ext_vector_type(8), aligned(8))) __bf16 bf16x8u;
typedef __attribute__((ext_vector_type(4), aligned(8))) __bf16 bf16x4a;
typedef __attribute__((ext_vector_type(4))) __bf16 bf16x4;
typedef __attribute__((ext_vector_type(4))) float f32x4;

union frag_u { struct { bf16x4a lo, hi; } p; bf16x8 v; };

// ---------------------------------------------------------------------------
// ws layout (13.3 MB total):
//   rtab    f32 [32][400]
//   costab  f32 [1024]  (pre-scaled by 223/224)
//   sintab  f32 [1024]  (pre-scaled by 223/224)
//   w2f     bf16 [20*3*6][64][8]  fragment-major w2, j ^ ((ka+icb)&1)*4
//   w1f     bf16 [12][64][8]      fragment-major w1 (grp = ks*6+ot), k>=60 -> 0
//   xp      bf16 [32][224][224][4] channels-last packed image
// ---------------------------------------------------------------------------

#define PACK_N   (NBATCH*IMGSZ*IMGSZ)
#define PACK_N4  (PACK_N/4)               // 401408, exact
#define PACK_B   ((PACK_N4 + 255)/256)    // 1568, exact
#define PREP_N   (ED*ED*20 + 12*64*8 + NBATCH*NR + NA + NBATCH)
#define PREP_B   ((PREP_N + 255)/256)

// merged image pack (4 px/thread, float4 loads) + tables + weight reorder
__global__ __launch_bounds__(256)
void prep_pack_kernel(const float* __restrict__ x,
                      const float* __restrict__ dist,
                      const float* __restrict__ w1,
                      const float* __restrict__ w2,
                      __bf16* __restrict__ xp,
                      float* __restrict__ rtab,
                      float* __restrict__ costab,
                      float* __restrict__ sintab,
                      __bf16* __restrict__ w2f,
                      __bf16* __restrict__ w1f,
                      float* __restrict__ theta_out) {
    const float PI = 3.14159265358979323846f;
    const float SC = 223.0f / 224.0f;
    int bid = blockIdx.x;

    if (bid < PACK_B) {                       // ---- image pack, 4 px/thread
        int i4 = bid*256 + threadIdx.x;
        if (i4 >= PACK_N4) return;
        int idx = i4 * 4;                     // pixel base; 50176 % 4 == 0 so
        int b  = idx / (IMGSZ*IMGSZ);         // all 4 px share one batch
        int px = idx - b*(IMGSZ*IMGSZ);
        const float* p = x + (size_t)b*3*IMGSZ*IMGSZ + px;
        f32x4 cr = *(const f32x4*)(p);
        f32x4 cg = *(const f32x4*)(p + IMGSZ*IMGSZ);
        f32x4 cb = *(const f32x4*)(p + 2*IMGSZ*IMGSZ);
        bf16x8 o0, o1;
        o0[0] = (__bf16)cr[0]; o0[1] = (__bf16)cg[0]; o0[2] = (__bf16)cb[0]; o0[3] = (__bf16)0.0f;
        o0[4] = (__bf16)cr[1]; o0[5] = (__bf16)cg[1]; o0[6] = (__bf16)cb[1]; o0[7] = (__bf16)0.0f;
        o1[0] = (__bf16)cr[2]; o1[1] = (__bf16)cg[2]; o1[2] = (__bf16)cb[2]; o1[3] = (__bf16)0.0f;
        o1[4] = (__bf16)cr[3]; o1[5] = (__bf16)cg[3]; o1[6] = (__bf16)cb[3]; o1[7] = (__bf16)0.0f;
        *(bf16x8*)(xp + (size_t)idx*4)     = o0;   // 16B, 32B-aligned
        *(bf16x8*)(xp + (size_t)idx*4 + 8) = o1;
        return;
    }

    int idx = (bid - PACK_B)*256 + threadIdx.x;
    if (idx < ED*ED*20) {
        // w2f: [(p*3+icb)*6+nt][lane][j], ic = icb*32+(lane>>4)*8+(j^sw)
        int j    = idx & 7;
        int lane = (idx >> 3) & 63;
        int grp  = idx >> 9;
        int nt   = grp % 6;
        int t    = grp / 6;
        int icb  = t % 3;
        int p    = t / 3;
        int sw   = (((p & 3) + icb) & 1) * 4;
        int oc = nt*16 + (lane & 15);
        int ic = icb*32 + (lane >> 4)*8 + (j ^ sw);
        w2f[idx] = (__bf16)w2[((size_t)(oc*ED + ic)*5 + (p >> 2))*4 + (p & 3)];
    } else if (idx < ED*ED*20 + 12*64*8) {
        // w1f: [grp=ks*6+ot][lane][j], A-frag value w1[oc][k]
        int i2   = idx - ED*ED*20;
        int j    = i2 & 7;
        int lane = (i2 >> 3) & 63;
        int grp  = i2 >> 9;
        int ks = grp / 6, ot = grp % 6;
        int oc = ot*16 + (lane & 15);
        int k  = ks*32 + (lane >> 4)*8 + j;
        w1f[i2] = (k < 60) ? (__bf16)w1[oc*60 + k] : (__bf16)0.0f;
    } else if (idx < ED*ED*20 + 12*64*8 + NBATCH*NR) {
        int i2 = idx - ED*ED*20 - 12*64*8;
        int b = i2 / NR, i = i2 % NR;
        float c0 = 0.2f + dist[b*4+0];
        float c1 = 0.2f + dist[b*4+1];
        float c2 = 0.2f + dist[b*4+2];
        float c3 = 0.2f + dist[b*4+3];
        float tmax = 0.5f * PI;
        float t  = tmax * ((float)i + 0.5f) / (float)NR;
        float t2 = t * t;
        float pt = t * (c0 + t2*(c1 + t2*(c2 + t2*c3)));
        float tm2 = tmax * tmax;
        float pm = tmax * (c0 + tm2*(c1 + tm2*(c2 + tm2*c3)));
        rtab[i2] = pt / pm * (0.5f * (float)IMGSZ);
    } else if (idx < ED*ED*20 + 12*64*8 + NBATCH*NR + NA) {
        int j = idx - ED*ED*20 - 12*64*8 - NBATCH*NR;
        float phi = 2.0f * PI * ((float)j + 0.5f) / (float)NA;
        costab[j] = cosf(phi) * SC;
        sintab[j] = sinf(phi) * SC;
    } else if (idx < PREP_N) {
        theta_out[idx - (ED*ED*20 + 12*64*8 + NBATCH*NR + NA)] = 0.5f * PI;
    }
}

// ---------------------------------------------------------------------------
// Mega kernel, wave-private + ASYNC-GATHER edition.
//
// Evidence chain: R2 (waves 20->16 cost 37%) => latency-concurrency bound
// (Little's law), NOT throughput.  R6-R8: resident waves can't increase
// (reg demand ~105-125; only (256,4) avoids spill).  R5/R9: cache-line and
// lane-locality changes null.  Remaining lever: OUTSTANDING LOADS PER WAVE.
// R0-R9 issued gathers(kr+1) at iteration end and consumed them immediately
// (prefetch distance 0): each wave serially pays ~400cy gather + ~300cy w2f
// per iteration.  This round splits sample into ISSUE (addresses + 10
// global_load_dwordx4 -> 40-VGPR payload, placed after conv1's epilogue)
// and FINISH (bilinear + LDS write, placed after conv2).  conv2's first
// vmcnt wait retires the earlier-issued gathers too (in-order FIFO), so the
// two waits MERGE (~400cy instead of ~700cy per iter).  Only possible
// because R9 removed in-loop barriers (each __syncthreads = vmcnt(0) drain).
//
// Payload live only across conv2 (acc1 dead): ~100 total regs < 128 cap.
// Single-buffered s_samp (same-wave read-then-write program order), LDS
// 32256 B.  Spill tripwire: WRITE_SIZE >> 12288 KB.  Weights for finish
// recomputed from (r, sn, cs) — nothing held beyond the 40 data regs.
// ---------------------------------------------------------------------------
__global__ __launch_bounds__(256, 4)
void mega_kernel(const __bf16* __restrict__ xp,
                 const __bf16* __restrict__ w1f_g,
                 const __bf16* __restrict__ w2f,
                 const float* __restrict__ b1,
                 const float* __restrict__ b2,
                 const float* __restrict__ rtab,
                 const float* __restrict__ costab,
                 const float* __restrict__ sintab,
                 float* __restrict__ out) {
    __shared__ __attribute__((aligned(16))) char smem[32256];
    __bf16* s_samp = (__bf16*)smem;               // [15][256] 7680B
    __bf16* t1f    = (__bf16*)(smem + 7680);      // [12 kk][4 qT][16 m][8]
    __bf16* s_w1f  = (__bf16*)(smem + 19968);     // [12 grp][64 lane][8]
    float*  red    = (float*)smem;                // [3][16][98] f32 (aliases)

    int tid = threadIdx.x;
    int bid = blockIdx.x;                       // 2048
    int r2 = bid & 15;
    int aq = (bid >> 4) & 3;
    int b  = bid >> 6;
    int wave = tid >> 6, lane = tid & 63, l15 = lane & 15, quad = lane >> 4;

    // stage w1 fragments into LDS (12288 B, coalesced); barrier below
    #pragma unroll
    for (int i = 0; i < 3; ++i)
        *(bf16x8*)(s_w1f + i*2048 + tid*8) = *(const bf16x8*)(w1f_g + i*2048 + tid*8);

    // wave-private az mapping (R9): conv1 wave w lane l15 owns a1 = l15*4+w;
    // its 4 k-az are sampled by lanes l15*4+j of wave w at slab elem w*64+lane.
    int col = ((lane >> 2) << 4) + wave*4 + (lane & 3);
    int az  = aq*256 + col;
    float sn = sintab[az];
    float cs = costab[az];
    int scol = wave*64 + lane;                  // storage slot (8B-aligned slabs)
    const __bf16* xpb = xp + (size_t)b*IMGSZ*IMGSZ*4;
    const float* rb = rtab + b*NR + r2*25;

    f32x4 acc2[6];
    #pragma unroll
    for (int nt = 0; nt < 6; ++nt) acc2[nt] = (f32x4){0.f,0.f,0.f,0.f};

    // gather payload: 5 points x 2 rows x 16B = 40 VGPRs
    bf16x8u ga[5], gb[5];

    // ISSUE: compute addresses, fire 10 global_load_dwordx4 (no waits here)
    auto sample_issue = [&](int kr) {
        #pragma unroll
        for (int q = 0; q < 5; ++q) {
            float r  = rb[kr*5 + q];                       // wave-uniform
            float gx = fmaf(r, sn, 111.5f);
            float gy = fmaf(r, cs, 111.5f);
            int ix = (int)floorf(gx), iy = (int)floorf(gy);
            ix = min(max(ix, 0), IMGSZ-2);
            iy = min(max(iy, 0), IMGSZ-2);
            const __bf16* img = xpb + ((size_t)iy*IMGSZ + ix)*4;
            ga[q] = *(const bf16x8u*)img;                  // row y: cols x0,x1
            gb[q] = *(const bf16x8u*)(img + IMGSZ*4);      // row y+1
        }
    };

    // FINISH: weights recomputed from (r,sn,cs); bilinear; LDS write.
    // By now conv2's vmcnt waits have retired the payload -> no stall here.
    auto sample_finish = [&](int kr) {
        #pragma unroll
        for (int q = 0; q < 5; ++q) {
            float r  = rb[kr*5 + q];
            float gx = fmaf(r, sn, 111.5f);
            float gy = fmaf(r, cs, 111.5f);
            float x0f = floorf(gx), y0f = floorf(gy);
            float wx1 = gx - x0f, wx0 = 1.0f - wx1;
            float wy1 = gy - y0f, wy0 = 1.0f - wy1;
            float w00 = wy0*wx0, w01 = wy0*wx1, w10 = wy1*wx0, w11 = wy1*wx1;
            #pragma unroll
            for (int c = 0; c < 3; ++c) {
                float v = w00*(float)ga[q][c] + w01*(float)ga[q][4+c]
                        + w10*(float)gb[q][c] + w11*(float)gb[q][4+c];
                s_samp[(c*5 + q)*SROW + scol] = (__bf16)v;
            }
        }
    };

    sample_issue(0);
    sample_finish(0);
    __syncthreads();   // w1f staged (only cross-wave LDS dependency)

    for (int kr = 0; kr < 5; ++kr) {
        // ---- conv1: a1 = l15*4 + wave; reads own wave's slab (no barrier)
        int cb = wave*64 + l15*4;
        f32x4 acc1[6];
        #pragma unroll
        for (int ot = 0; ot < 6; ++ot) acc1[ot] = (f32x4){0.f,0.f,0.f,0.f};

        frag_u fa, fb;
        fa.p.lo = *(const bf16x4a*)&s_samp[(quad*2    )*SROW + cb];
        fa.p.hi = *(const bf16x4a*)&s_samp[(quad*2 + 1)*SROW + cb];
        fb.p.lo = *(const bf16x4a*)&s_samp[(8 + quad*2)*SROW + cb];
        if (quad == 3) fb.p.hi = (bf16x4a){};
        else           fb.p.hi = *(const bf16x4a*)&s_samp[(9 + quad*2)*SROW + cb];

        #pragma unroll
        for (int ot = 0; ot < 6; ++ot) {
            bf16x8 wf0 = *(const bf16x8*)(s_w1f + (ot     )*512 + lane*8);
            bf16x8 wf1 = *(const bf16x8*)(s_w1f + (6 + ot )*512 + lane*8);
            acc1[ot] = __builtin_amdgcn_mfma_f32_16x16x32_bf16(wf0, fa.v, acc1[ot], 0, 0, 0);
            acc1[ot] = __builtin_amdgcn_mfma_f32_16x16x32_bf16(wf1, fb.v, acc1[ot], 0, 0, 0);
        }

        // epilogue: D col=l15 -> a1 = l15*4+wave: a2l = l15, ka = wave.
        #pragma unroll
        for (int ot = 0; ot < 6; ++ot) {
            f32x4 v = acc1[ot] + *(const f32x4*)(b1 + ot*16 + quad*4);
            bf16x4a wv;
            wv[0] = (__bf16)v[0]; wv[1] = (__bf16)v[1];
            wv[2] = (__bf16)v[2]; wv[3] = (__bf16)v[3];
            int icbase = ot*16 + quad*4;
            int kk = wave*3 + (icbase >> 5);
            int qT = (icbase >> 3) & 3;
            int jb = (icbase & 7) ^ ((kk & 1)*4);
            *(bf16x4a*)&t1f[((kk*4 + qT)*16 + l15)*8 + jb] = wv;
        }

        // ---- ISSUE gathers(kr+1) BEFORE conv2's loads: conv2's vmcnt waits
        // retire them "for free"; finish after conv2 then has no stall.
        if (kr < 4) sample_issue(kr + 1);
        __builtin_amdgcn_sched_barrier(0);   // pin issue order (no sinking)

        // ---- conv2: wave's ka = wave; 3 k-steps (t1f same-wave RAW, lgkmcnt)
        #pragma unroll
        for (int icb = 0; icb < 3; ++icb) {
            int kk = wave*3 + icb;
            int p  = kr*4 + wave;
            bf16x8 af = *(const bf16x8*)&t1f[(kk*64 + lane)*8];   // lane-contig
            const __bf16* wp = w2f + (size_t)((p*3 + icb)*6)*512 + lane*8;
            #pragma unroll
            for (int nt = 0; nt < 6; ++nt) {
                bf16x8 bf = *(const bf16x8*)(wp + nt*512);
                acc2[nt] = __builtin_amdgcn_mfma_f32_16x16x32_bf16(af, bf, acc2[nt], 0, 0, 0);
            }
        }

        // ---- FINISH: payload already landed; pure VALU + ds_write.
        // Same-wave s_samp read(conv1)->write(finish) ordered by program order.
        if (kr < 4) sample_finish(kr + 1);
    }

    // ---- ka-quarter reduction (red aliases s_samp+t1f head; w1f safe)
    __syncthreads();
    if (wave) {
        float* rw = red + (wave - 1)*1568;     // 16*98
        #pragma unroll
        for (int nt = 0; nt < 6; ++nt)
            #pragma unroll
            for (int r = 0; r < 4; ++r)
                rw[(quad*4 + r)*98 + nt*16 + l15] = acc2[nt][r];
    }
    __syncthreads();
    if (wave == 0) {
        size_t ob = ((size_t)b*1024 + r2*64 + aq*16)*ED;
        #pragma unroll
        for (int nt = 0; nt < 6; ++nt) {
            int oc = nt*16 + l15;
            float bias = b2[oc];
            #pragma unroll
            for (int r = 0; r < 4; ++r) {
                int row = quad*4 + r;
                float v = acc2[nt][r] + bias
                        + red[row*98 + oc]
                        + red[1568 + row*98 + oc]
                        + red[3136 + row*98 + oc];
                out[ob + (size_t)row*ED + oc] = v;
            }
        }
    }
}

extern "C" void kernel_launch(void* const* d_in, const int* in_sizes, int n_in,
                              void* d_out, int out_size, void* d_ws, size_t ws_size,
                              hipStream_t stream) {
    const float* x    = (const float*)d_in[0];
    const float* dist = (const float*)d_in[1];
    const float* w1   = (const float*)d_in[2];
    const float* b1   = (const float*)d_in[3];
    const float* w2   = (const float*)d_in[4];
    const float* b2   = (const float*)d_in[5];
    float* out = (float*)d_out;

    float* rtab   = (float*)d_ws;                 // 12800 f32
    float* costab = rtab + NBATCH*NR;             // 1024 f32
    float* sintab = costab + NA;                  // 1024 f32
    __bf16* w2f   = (__bf16*)(sintab + NA);       // 184320 bf16
    __bf16* w1f   = w2f + ED*ED*20;               // 6144 bf16
    __bf16* xp    = w1f + 12*64*8;                // 32*224*224*4 bf16 (12.8MB)

    float* theta_out = out + (size_t)NBATCH*1024*ED;

    prep_pack_kernel<<<PACK_B + PREP_B, 256, 0, stream>>>(
        x, dist, w1, w2, xp, rtab, costab, sintab, w2f, w1f, theta_out);
    mega_kernel<<<NBATCH*16*4, 256, 0, stream>>>(
        xp, w1f, w2f, b1, b2, rtab, costab, sintab, out);
}